// Round 1
// baseline (1302.782 us; speedup 1.0000x reference)
//
#include <hip/hip_runtime.h>
#include <hip/hip_bf16.h>
#include <cstdint>
#include <cstddef>

#define B_ROWS 16384
#define WIDTH  1024
#define HID    2048
#define NBLK   4
#define YDIM   16
#define OUTD   256
#define KIN    128          // input dim 81 padded to 128
#define MAXM_PER_CLASS 4096

typedef __attribute__((ext_vector_type(8))) short short8;
typedef __attribute__((ext_vector_type(4))) float f32x4;

__device__ __forceinline__ unsigned short f2bf(float f) {
    union { float f; uint32_t u; } v; v.f = f;
    uint32_t u = v.u;
    uint32_t r = (u + 0x7FFFu + ((u >> 16) & 1u)) >> 16;
    return (unsigned short)r;
}

__device__ __forceinline__ void gload_lds16(const void* g, void* l) {
    __builtin_amdgcn_global_load_lds(
        (const __attribute__((address_space(1))) void*)g,
        (__attribute__((address_space(3))) void*)l, 16, 0, 0);
}

// ---------------------------------------------------------------------------
// prep: build padded bf16 input rows [B,128] = [theta(64) | lambda(1) | y_oh(16) | 0...]
// and argmax-route rows into per-class buckets.
__global__ __launch_bounds__(128)
void prep_x_k(const float* __restrict__ theta, const float* __restrict__ lam,
              const float* __restrict__ yoh, unsigned short* __restrict__ xb,
              int* __restrict__ counts, int* __restrict__ bucket)
{
    int row = blockIdx.x, j = threadIdx.x;
    float v;
    if (j < 64)       v = theta[(size_t)row * 64 + j];
    else if (j == 64) v = lam[row];
    else if (j < 81)  v = yoh[(size_t)row * 16 + (j - 65)];
    else              v = 0.f;
    xb[(size_t)row * KIN + j] = f2bf(v);
    if (j == 0) {
        const float* yr = yoh + (size_t)row * 16;
        int best = 0; float bv = yr[0];
        #pragma unroll
        for (int t2 = 1; t2 < 16; ++t2) { float q = yr[t2]; if (q > bv) { bv = q; best = t2; } }
        int pos = atomicAdd(&counts[best], 1);
        if (pos < MAXM_PER_CLASS) bucket[best * MAXM_PER_CLASS + pos] = row;
    }
}

// ---------------------------------------------------------------------------
// batched transpose + fp32->bf16: src [R][C] -> dst [C][RP], zero-padding rows R..RP
__global__ __launch_bounds__(256)
void tcvt_k(const float* __restrict__ src, unsigned short* __restrict__ dst,
            int R, int C, int RP)
{
    int b = blockIdx.z;
    src += (size_t)b * R * C;
    dst += (size_t)b * C * RP;
    __shared__ float tile[32][33];
    int tx = threadIdx.x & 31, ty = threadIdx.x >> 5;   // 32 x 8
    int c0 = blockIdx.x * 32, r0 = blockIdx.y * 32;
    #pragma unroll
    for (int p = 0; p < 4; ++p) {
        int r = r0 + p * 8 + ty;
        float v = (r < R) ? src[(size_t)r * C + c0 + tx] : 0.f;
        tile[p * 8 + ty][tx] = v;
    }
    __syncthreads();
    #pragma unroll
    for (int p = 0; p < 4; ++p) {
        int c = c0 + p * 8 + ty;
        dst[(size_t)c * RP + r0 + tx] = f2bf(tile[tx][p * 8 + ty]);
    }
}

// ---------------------------------------------------------------------------
// LayerNorm: h fp32 [B,1024] -> z bf16 [B,1024]
__global__ __launch_bounds__(256)
void ln_k(const float* __restrict__ h, const float* __restrict__ g,
          const float* __restrict__ bb, unsigned short* __restrict__ z)
{
    int row = blockIdx.x;
    int t = threadIdx.x;
    const float4 v = ((const float4*)(h + (size_t)row * WIDTH))[t];
    float s  = v.x + v.y + v.z + v.w;
    float s2 = v.x * v.x + v.y * v.y + v.z * v.z + v.w * v.w;
    #pragma unroll
    for (int off = 32; off > 0; off >>= 1) {
        s  += __shfl_down(s, off);
        s2 += __shfl_down(s2, off);
    }
    __shared__ float red[8];
    int wv = t >> 6;
    if ((t & 63) == 0) { red[wv] = s; red[4 + wv] = s2; }
    __syncthreads();
    float st = 0.f, s2t = 0.f;
    #pragma unroll
    for (int i = 0; i < 4; ++i) { st += red[i]; s2t += red[4 + i]; }
    float mu  = st * (1.f / 1024.f);
    float var = s2t * (1.f / 1024.f) - mu * mu;
    float rs  = rsqrtf(var + 1e-5f);
    int c = t * 4;
    float4 gg  = ((const float4*)g)[t];
    float4 bbv = ((const float4*)bb)[t];
    ushort4 o;
    o.x = f2bf((v.x - mu) * rs * gg.x + bbv.x);
    o.y = f2bf((v.y - mu) * rs * gg.y + bbv.y);
    o.z = f2bf((v.z - mu) * rs * gg.z + bbv.z);
    o.w = f2bf((v.w - mu) * rs * gg.w + bbv.w);
    (void)c;
    ((ushort4*)(z + (size_t)row * WIDTH))[t] = o;
}

// ---------------------------------------------------------------------------
// 128x128x(BK=64) bf16 MFMA GEMM, B given transposed [N][K].
// EPI: 0 = +bias, GELU -> Cf (fp32)
//      1 = +bias, SiLU -> Cb (bf16)
//      2 = Cf += rscale*( . + bias); optional Cb = bf16(Cf)
//      3 = bucketed head: gathered A rows, out = . + bias (fp32), masked by count
template<int EPI>
__global__ __launch_bounds__(256)
void gemm_k(const short* __restrict__ A, const short* __restrict__ BT,
            const float* __restrict__ bias,
            float* __restrict__ Cf, unsigned short* __restrict__ Cb,
            const float* __restrict__ rs_ptr, int rs_idx, int writeHb,
            const int* __restrict__ counts, const int* __restrict__ bucket,
            float* __restrict__ outp,
            int N, int K, int ntN)
{
    __shared__ short lsA[128 * 64];
    __shared__ short lsB[128 * 64];
    __shared__ int rowsLds[128];

    int tid = threadIdx.x;
    int w = tid >> 6, lane = tid & 63;

    int bm = 0, bn = 0, m0 = 0, cnt = 0;
    if (EPI == 3) {
        int cls = blockIdx.z;
        cnt = counts[cls];
        if (cnt > MAXM_PER_CLASS) cnt = MAXM_PER_CLASS;
        m0 = blockIdx.y * 128;
        if (m0 >= cnt) return;                       // uniform exit
        bn = blockIdx.x;
        if (tid < 128) rowsLds[tid] = bucket[cls * MAXM_PER_CLASS + m0 + tid];
        __syncthreads();
        BT   += (size_t)cls * OUTD * WIDTH;
        bias += cls * OUTD;
    } else {
        int nwg = gridDim.x;
        int wg  = blockIdx.x;
        int cpx = nwg >> 3;                          // grids are %8==0
        int swz = (wg & 7) * cpx + (wg >> 3);        // bijective XCD swizzle
        bm = swz / ntN; bn = swz % ntN;
    }

    const int sr = lane >> 3;    // 0..7
    const int ss = lane & 7;     // 0..7

    f32x4 acc[4][4];
    #pragma unroll
    for (int i = 0; i < 4; ++i)
        #pragma unroll
        for (int j = 0; j < 4; ++j) acc[i][j] = (f32x4)(0.f);

    const int wm = w >> 1, wn = w & 1;
    const int nkt = K >> 6;

    for (int kt = 0; kt < nkt; ++kt) {
        // stage A tile (128x64 bf16), XOR-swizzled content via pre-swizzled source
        #pragma unroll
        for (int c = 0; c < 4; ++c) {
            int r  = w * 32 + c * 8 + sr;
            int sg = ss ^ (r & 7);
            long grow = (EPI == 3) ? (long)rowsLds[r] : ((long)bm * 128 + r);
            const short* ga = A + (size_t)grow * K + kt * 64 + sg * 8;
            gload_lds16(ga, &lsA[(w * 32 + c * 8) * 64]);
        }
        // stage B tile
        #pragma unroll
        for (int c = 0; c < 4; ++c) {
            int r  = w * 32 + c * 8 + sr;
            int sg = ss ^ (r & 7);
            const short* gb = BT + (size_t)(bn * 128 + r) * K + kt * 64 + sg * 8;
            gload_lds16(gb, &lsB[(w * 32 + c * 8) * 64]);
        }
        __syncthreads();
        #pragma unroll
        for (int ks = 0; ks < 2; ++ks) {
            short8 af[4], bf[4];
            #pragma unroll
            for (int m = 0; m < 4; ++m) {
                int r = wm * 64 + m * 16 + (lane & 15);
                int s = ks * 4 + (lane >> 4);
                af[m] = *(const short8*)&lsA[r * 64 + (s ^ (r & 7)) * 8];
            }
            #pragma unroll
            for (int n = 0; n < 4; ++n) {
                int r = wn * 64 + n * 16 + (lane & 15);
                int s = ks * 4 + (lane >> 4);
                bf[n] = *(const short8*)&lsB[r * 64 + (s ^ (r & 7)) * 8];
            }
            #pragma unroll
            for (int m = 0; m < 4; ++m)
                #pragma unroll
                for (int n = 0; n < 4; ++n)
                    acc[m][n] = __builtin_amdgcn_mfma_f32_16x16x32_bf16(af[m], bf[n], acc[m][n], 0, 0, 0);
        }
        __syncthreads();
    }

    float rscale = (EPI == 2) ? rs_ptr[rs_idx] : 0.f;
    #pragma unroll
    for (int m = 0; m < 4; ++m) {
        #pragma unroll
        for (int reg = 0; reg < 4; ++reg) {
            int lr = wm * 64 + m * 16 + (lane >> 4) * 4 + reg;
            #pragma unroll
            for (int n = 0; n < 4; ++n) {
                int lc = wn * 64 + n * 16 + (lane & 15);
                float v = acc[m][n][reg];
                if (EPI == 0) {
                    size_t idx = ((size_t)bm * 128 + lr) * (size_t)N + bn * 128 + lc;
                    float x = v + bias[bn * 128 + lc];
                    Cf[idx] = 0.5f * x * (1.f + erff(x * 0.70710678118f));
                } else if (EPI == 1) {
                    size_t idx = ((size_t)bm * 128 + lr) * (size_t)N + bn * 128 + lc;
                    float x = v + bias[bn * 128 + lc];
                    Cb[idx] = f2bf(x / (1.f + __expf(-x)));
                } else if (EPI == 2) {
                    size_t idx = ((size_t)bm * 128 + lr) * (size_t)N + bn * 128 + lc;
                    float x = v + bias[bn * 128 + lc];
                    float hv = Cf[idx] + rscale * x;
                    Cf[idx] = hv;
                    if (writeHb) Cb[idx] = f2bf(hv);
                } else {
                    if (m0 + lr < cnt) {
                        int orow = rowsLds[lr];
                        int oc = bn * 128 + lc;
                        outp[(size_t)orow * OUTD + oc] = v + bias[oc];
                    }
                }
            }
        }
    }
}

// ---------------------------------------------------------------------------
extern "C" void kernel_launch(void* const* d_in, const int* in_sizes, int n_in,
                              void* d_out, int out_size, void* d_ws, size_t ws_size,
                              hipStream_t stream)
{
    const float* theta = (const float*)d_in[0];
    const float* lam   = (const float*)d_in[1];
    const float* yoh   = (const float*)d_in[2];
    const float* W_in  = (const float*)d_in[3];
    const float* b_in  = (const float*)d_in[4];
    const float* ln_g  = (const float*)d_in[5];
    const float* ln_b  = (const float*)d_in[6];
    const float* w1    = (const float*)d_in[7];
    const float* b1    = (const float*)d_in[8];
    const float* w2    = (const float*)d_in[9];
    const float* b2    = (const float*)d_in[10];
    const float* rsc   = (const float*)d_in[11];
    const float* Wh    = (const float*)d_in[12];
    const float* bh    = (const float*)d_in[13];
    float* out = (float*)d_out;

    char* p = (char*)d_ws;
    auto alloc = [&](size_t bytes) -> char* {
        char* r = p; p += (bytes + 255) & ~(size_t)255; return r;
    };
    float*          h    = (float*)         alloc((size_t)B_ROWS * WIDTH * 4);
    unsigned short* hb   = (unsigned short*)alloc((size_t)B_ROWS * WIDTH * 2);
    unsigned short* z    = (unsigned short*)alloc((size_t)B_ROWS * WIDTH * 2);
    unsigned short* t    = (unsigned short*)alloc((size_t)B_ROWS * HID * 2);
    unsigned short* xb   = (unsigned short*)alloc((size_t)B_ROWS * KIN * 2);
    unsigned short* w1T  = (unsigned short*)alloc((size_t)NBLK * HID * WIDTH * 2);
    unsigned short* w2T  = (unsigned short*)alloc((size_t)NBLK * WIDTH * HID * 2);
    unsigned short* WhT  = (unsigned short*)alloc((size_t)YDIM * OUTD * WIDTH * 2);
    unsigned short* WiT  = (unsigned short*)alloc((size_t)WIDTH * KIN * 2);
    int*            bucket = (int*)alloc((size_t)YDIM * MAXM_PER_CLASS * 4);
    int*            counts = (int*)alloc(256);

    hipMemsetAsync(bucket, 0, (size_t)YDIM * MAXM_PER_CLASS * 4, stream);
    hipMemsetAsync(counts, 0, 256, stream);

    // prep inputs + buckets
    prep_x_k<<<B_ROWS, 128, 0, stream>>>(theta, lam, yoh, xb, counts, bucket);

    // weight conversions (transpose to [N][K] bf16)
    tcvt_k<<<dim3(WIDTH / 32, KIN / 32, 1),    256, 0, stream>>>(W_in, WiT, 81,   WIDTH, KIN);
    tcvt_k<<<dim3(HID / 32,   WIDTH / 32, 4),  256, 0, stream>>>(w1,   w1T, WIDTH, HID,  WIDTH);
    tcvt_k<<<dim3(WIDTH / 32, HID / 32, 4),    256, 0, stream>>>(w2,   w2T, HID,  WIDTH, HID);
    tcvt_k<<<dim3(OUTD / 32,  WIDTH / 32, 16), 256, 0, stream>>>(Wh,   WhT, WIDTH, OUTD, WIDTH);

    // input GEMM + GELU -> h fp32
    gemm_k<0><<<(B_ROWS / 128) * (WIDTH / 128), 256, 0, stream>>>(
        (const short*)xb, (const short*)WiT, b_in, h, nullptr,
        nullptr, 0, 0, nullptr, nullptr, nullptr, WIDTH, KIN, WIDTH / 128);

    for (int i = 0; i < NBLK; ++i) {
        ln_k<<<B_ROWS, 256, 0, stream>>>(h, ln_g + i * WIDTH, ln_b + i * WIDTH, z);
        gemm_k<1><<<(B_ROWS / 128) * (HID / 128), 256, 0, stream>>>(
            (const short*)z, (const short*)(w1T + (size_t)i * HID * WIDTH), b1 + i * HID,
            nullptr, t, nullptr, 0, 0, nullptr, nullptr, nullptr, HID, WIDTH, HID / 128);
        gemm_k<2><<<(B_ROWS / 128) * (WIDTH / 128), 256, 0, stream>>>(
            (const short*)t, (const short*)(w2T + (size_t)i * WIDTH * HID), b2 + i * WIDTH,
            h, hb, rsc, i, (i == NBLK - 1) ? 1 : 0, nullptr, nullptr, nullptr,
            WIDTH, HID, WIDTH / 128);
    }

    // bucketed head GEMM
    gemm_k<3><<<dim3(OUTD / 128, MAXM_PER_CLASS / 128, YDIM), 256, 0, stream>>>(
        (const short*)hb, (const short*)WhT, bh, nullptr, nullptr,
        nullptr, 0, 0, counts, bucket, out, OUTD, WIDTH, OUTD / 128);

    (void)in_sizes; (void)n_in; (void)out_size; (void)ws_size; (void)rsc;
}

// Round 3
// 1119.181 us; speedup vs baseline: 1.1640x; 1.1640x over previous
//
#include <hip/hip_runtime.h>
#include <hip/hip_bf16.h>
#include <cstdint>
#include <cstddef>

#define B_ROWS 16384
#define WIDTH  1024
#define HID    2048
#define NBLK   4
#define YDIM   16
#define OUTD   256
#define KIN    128          // input dim 81 padded to 128
#define MAXM_PER_CLASS 4096

typedef __attribute__((ext_vector_type(8))) short short8;
typedef __attribute__((ext_vector_type(4))) float f32x4;

__device__ __forceinline__ unsigned short f2bf(float f) {
    union { float f; uint32_t u; } v; v.f = f;
    uint32_t u = v.u;
    uint32_t r = (u + 0x7FFFu + ((u >> 16) & 1u)) >> 16;
    return (unsigned short)r;
}

__device__ __forceinline__ void gload_lds16(const void* g, void* l) {
    __builtin_amdgcn_global_load_lds(
        (const __attribute__((address_space(1))) void*)g,
        (__attribute__((address_space(3))) void*)l, 16, 0, 0);
}

// ---------------------------------------------------------------------------
// x build only (no atomics): padded bf16 rows [B,128] = [theta|lambda|y_oh|0]
// 256 threads = 2 rows per block.
__global__ __launch_bounds__(256)
void prep_x_k(const float* __restrict__ theta, const float* __restrict__ lam,
              const float* __restrict__ yoh, unsigned short* __restrict__ xb)
{
    int tid = threadIdx.x;
    int row = blockIdx.x * 2 + (tid >> 7);
    int j = tid & 127;
    float v;
    if (j < 64)       v = theta[(size_t)row * 64 + j];
    else if (j == 64) v = lam[row];
    else if (j < 81)  v = yoh[(size_t)row * 16 + (j - 65)];
    else              v = 0.f;
    xb[(size_t)row * KIN + j] = f2bf(v);
}

// ---------------------------------------------------------------------------
// argmax-route rows into per-class buckets; LDS-aggregated histogram, one
// global atomic per (block, class) to cache-line-padded counters.
__global__ __launch_bounds__(256)
void bucket_k(const float* __restrict__ yoh, int* __restrict__ counts,
              int* __restrict__ bucket)
{
    __shared__ int cnt_lds[16];
    __shared__ int base_lds[16];
    int tid = threadIdx.x;
    if (tid < 16) cnt_lds[tid] = 0;
    __syncthreads();
    int row = blockIdx.x * 256 + tid;
    const float4* yr = (const float4*)(yoh + (size_t)row * 16);
    int best = 0; float bv = -3.0e38f;
    #pragma unroll
    for (int p = 0; p < 4; ++p) {
        float4 v = yr[p];
        if (v.x > bv) { bv = v.x; best = p * 4 + 0; }
        if (v.y > bv) { bv = v.y; best = p * 4 + 1; }
        if (v.z > bv) { bv = v.z; best = p * 4 + 2; }
        if (v.w > bv) { bv = v.w; best = p * 4 + 3; }
    }
    int mypos = atomicAdd(&cnt_lds[best], 1);
    __syncthreads();
    if (tid < 16) base_lds[tid] = atomicAdd(&counts[tid * 32], cnt_lds[tid]);
    __syncthreads();
    int pos = base_lds[best] + mypos;
    if (pos < MAXM_PER_CLASS) bucket[best * MAXM_PER_CLASS + pos] = row;
}

// ---------------------------------------------------------------------------
// batched transpose + fp32->bf16: src [R][C] -> dst [C][RP], zero-padding rows R..RP
__global__ __launch_bounds__(256)
void tcvt_k(const float* __restrict__ src, unsigned short* __restrict__ dst,
            int R, int C, int RP)
{
    int b = blockIdx.z;
    src += (size_t)b * R * C;
    dst += (size_t)b * C * RP;
    __shared__ float tile[32][33];
    int tx = threadIdx.x & 31, ty = threadIdx.x >> 5;   // 32 x 8
    int c0 = blockIdx.x * 32, r0 = blockIdx.y * 32;
    #pragma unroll
    for (int p = 0; p < 4; ++p) {
        int r = r0 + p * 8 + ty;
        float v = (r < R) ? src[(size_t)r * C + c0 + tx] : 0.f;
        tile[p * 8 + ty][tx] = v;
    }
    __syncthreads();
    #pragma unroll
    for (int p = 0; p < 4; ++p) {
        int c = c0 + p * 8 + ty;
        dst[(size_t)c * RP + r0 + tx] = f2bf(tile[tx][p * 8 + ty]);
    }
}

// ---------------------------------------------------------------------------
// LayerNorm: h fp32 [B,1024] -> z bf16 [B,1024]
__global__ __launch_bounds__(256)
void ln_k(const float* __restrict__ h, const float* __restrict__ g,
          const float* __restrict__ bb, unsigned short* __restrict__ z)
{
    int row = blockIdx.x;
    int t = threadIdx.x;
    const float4 v = ((const float4*)(h + (size_t)row * WIDTH))[t];
    float s  = v.x + v.y + v.z + v.w;
    float s2 = v.x * v.x + v.y * v.y + v.z * v.z + v.w * v.w;
    #pragma unroll
    for (int off = 32; off > 0; off >>= 1) {
        s  += __shfl_down(s, off);
        s2 += __shfl_down(s2, off);
    }
    __shared__ float red[8];
    int wv = t >> 6;
    if ((t & 63) == 0) { red[wv] = s; red[4 + wv] = s2; }
    __syncthreads();
    float st = 0.f, s2t = 0.f;
    #pragma unroll
    for (int i = 0; i < 4; ++i) { st += red[i]; s2t += red[4 + i]; }
    float mu  = st * (1.f / 1024.f);
    float var = s2t * (1.f / 1024.f) - mu * mu;
    float rs  = rsqrtf(var + 1e-5f);
    float4 gg  = ((const float4*)g)[t];
    float4 bbv = ((const float4*)bb)[t];
    ushort4 o;
    o.x = f2bf((v.x - mu) * rs * gg.x + bbv.x);
    o.y = f2bf((v.y - mu) * rs * gg.y + bbv.y);
    o.z = f2bf((v.z - mu) * rs * gg.z + bbv.z);
    o.w = f2bf((v.w - mu) * rs * gg.w + bbv.w);
    ((ushort4*)(z + (size_t)row * WIDTH))[t] = o;
}

// ---------------------------------------------------------------------------
// 128x128x(BK=64) bf16 MFMA GEMM, B given transposed [N][K].
// EPI: 0 = +bias, GELU -> Cf (fp32)
//      1 = +bias, SiLU -> Cb (bf16)
//      2 = Cf += rscale*( . + bias); optional Cb = bf16(Cf)
//      3 = bucketed head: gathered A rows, out = . + bias (fp32), masked by count
template<int EPI>
__global__ __launch_bounds__(256)
void gemm_k(const short* __restrict__ A, const short* __restrict__ BT,
            const float* __restrict__ bias,
            float* __restrict__ Cf, unsigned short* __restrict__ Cb,
            const float* __restrict__ rs_ptr, int rs_idx, int writeHb,
            const int* __restrict__ counts, const int* __restrict__ bucket,
            float* __restrict__ outp,
            int N, int K, int ntN)
{
    __shared__ short lsA[128 * 64];
    __shared__ short lsB[128 * 64];
    __shared__ int rowsLds[128];

    int tid = threadIdx.x;
    int w = tid >> 6, lane = tid & 63;

    int bm = 0, bn = 0, m0 = 0, cnt = 0;
    if (EPI == 3) {
        int cls = blockIdx.z;
        cnt = counts[cls * 32];
        if (cnt > MAXM_PER_CLASS) cnt = MAXM_PER_CLASS;
        m0 = blockIdx.y * 128;
        if (m0 >= cnt) return;                       // uniform exit
        bn = blockIdx.x;
        if (tid < 128) rowsLds[tid] = bucket[cls * MAXM_PER_CLASS + m0 + tid];
        __syncthreads();
        BT   += (size_t)cls * OUTD * WIDTH;
        bias += cls * OUTD;
    } else {
        int nwg = gridDim.x;
        int wg  = blockIdx.x;
        int cpx = nwg >> 3;                          // grids are %8==0
        int swz = (wg & 7) * cpx + (wg >> 3);        // bijective XCD swizzle
        bm = swz / ntN; bn = swz % ntN;
    }

    const int sr = lane >> 3;    // 0..7
    const int ss = lane & 7;     // 0..7

    f32x4 acc[4][4];
    #pragma unroll
    for (int i = 0; i < 4; ++i)
        #pragma unroll
        for (int j = 0; j < 4; ++j) acc[i][j] = (f32x4)(0.f);

    const int wm = w >> 1, wn = w & 1;
    const int nkt = K >> 6;

    for (int kt = 0; kt < nkt; ++kt) {
        // stage A tile (128x64 bf16), XOR-swizzled content via pre-swizzled source
        #pragma unroll
        for (int c = 0; c < 4; ++c) {
            int r  = w * 32 + c * 8 + sr;
            int sg = ss ^ (r & 7);
            long grow = (EPI == 3) ? (long)rowsLds[r] : ((long)bm * 128 + r);
            const short* ga = A + (size_t)grow * K + kt * 64 + sg * 8;
            gload_lds16(ga, &lsA[(w * 32 + c * 8) * 64]);
        }
        // stage B tile
        #pragma unroll
        for (int c = 0; c < 4; ++c) {
            int r  = w * 32 + c * 8 + sr;
            int sg = ss ^ (r & 7);
            const short* gb = BT + (size_t)(bn * 128 + r) * K + kt * 64 + sg * 8;
            gload_lds16(gb, &lsB[(w * 32 + c * 8) * 64]);
        }
        __syncthreads();
        #pragma unroll
        for (int ks = 0; ks < 2; ++ks) {
            short8 af[4], bf[4];
            #pragma unroll
            for (int m = 0; m < 4; ++m) {
                int r = wm * 64 + m * 16 + (lane & 15);
                int s = ks * 4 + (lane >> 4);
                af[m] = *(const short8*)&lsA[r * 64 + (s ^ (r & 7)) * 8];
            }
            #pragma unroll
            for (int n = 0; n < 4; ++n) {
                int r = wn * 64 + n * 16 + (lane & 15);
                int s = ks * 4 + (lane >> 4);
                bf[n] = *(const short8*)&lsB[r * 64 + (s ^ (r & 7)) * 8];
            }
            #pragma unroll
            for (int m = 0; m < 4; ++m)
                #pragma unroll
                for (int n = 0; n < 4; ++n)
                    acc[m][n] = __builtin_amdgcn_mfma_f32_16x16x32_bf16(af[m], bf[n], acc[m][n], 0, 0, 0);
        }
        __syncthreads();
    }

    float rscale = (EPI == 2) ? rs_ptr[rs_idx] : 0.f;
    #pragma unroll
    for (int m = 0; m < 4; ++m) {
        #pragma unroll
        for (int reg = 0; reg < 4; ++reg) {
            int lr = wm * 64 + m * 16 + (lane >> 4) * 4 + reg;
            #pragma unroll
            for (int n = 0; n < 4; ++n) {
                int lc = wn * 64 + n * 16 + (lane & 15);
                float v = acc[m][n][reg];
                if (EPI == 0) {
                    size_t idx = ((size_t)bm * 128 + lr) * (size_t)N + bn * 128 + lc;
                    float x = v + bias[bn * 128 + lc];
                    Cf[idx] = 0.5f * x * (1.f + erff(x * 0.70710678118f));
                } else if (EPI == 1) {
                    size_t idx = ((size_t)bm * 128 + lr) * (size_t)N + bn * 128 + lc;
                    float x = v + bias[bn * 128 + lc];
                    Cb[idx] = f2bf(x / (1.f + __expf(-x)));
                } else if (EPI == 2) {
                    size_t idx = ((size_t)bm * 128 + lr) * (size_t)N + bn * 128 + lc;
                    float x = v + bias[bn * 128 + lc];
                    float hv = Cf[idx] + rscale * x;
                    Cf[idx] = hv;
                    if (writeHb) Cb[idx] = f2bf(hv);
                } else {
                    if (m0 + lr < cnt) {
                        int orow = rowsLds[lr];
                        int oc = bn * 128 + lc;
                        outp[(size_t)orow * OUTD + oc] = v + bias[oc];
                    }
                }
            }
        }
    }
}

// ---------------------------------------------------------------------------
extern "C" void kernel_launch(void* const* d_in, const int* in_sizes, int n_in,
                              void* d_out, int out_size, void* d_ws, size_t ws_size,
                              hipStream_t stream)
{
    const float* theta = (const float*)d_in[0];
    const float* lam   = (const float*)d_in[1];
    const float* yoh   = (const float*)d_in[2];
    const float* W_in  = (const float*)d_in[3];
    const float* b_in  = (const float*)d_in[4];
    const float* ln_g  = (const float*)d_in[5];
    const float* ln_b  = (const float*)d_in[6];
    const float* w1    = (const float*)d_in[7];
    const float* b1    = (const float*)d_in[8];
    const float* w2    = (const float*)d_in[9];
    const float* b2    = (const float*)d_in[10];
    const float* rsc   = (const float*)d_in[11];
    const float* Wh    = (const float*)d_in[12];
    const float* bh    = (const float*)d_in[13];
    float* out = (float*)d_out;

    char* p = (char*)d_ws;
    auto alloc = [&](size_t bytes) -> char* {
        char* r = p; p += (bytes + 255) & ~(size_t)255; return r;
    };
    float*          h    = (float*)         alloc((size_t)B_ROWS * WIDTH * 4);
    unsigned short* hb   = (unsigned short*)alloc((size_t)B_ROWS * WIDTH * 2);
    unsigned short* z    = (unsigned short*)alloc((size_t)B_ROWS * WIDTH * 2);
    unsigned short* t    = (unsigned short*)alloc((size_t)B_ROWS * HID * 2);
    unsigned short* xb   = (unsigned short*)alloc((size_t)B_ROWS * KIN * 2);
    unsigned short* w1T  = (unsigned short*)alloc((size_t)NBLK * HID * WIDTH * 2);
    unsigned short* w2T  = (unsigned short*)alloc((size_t)NBLK * WIDTH * HID * 2);
    unsigned short* WhT  = (unsigned short*)alloc((size_t)YDIM * OUTD * WIDTH * 2);
    unsigned short* WiT  = (unsigned short*)alloc((size_t)WIDTH * KIN * 2);
    int*            bucket = (int*)alloc((size_t)YDIM * MAXM_PER_CLASS * 4);
    int*            counts = (int*)alloc(16 * 32 * 4);

    hipMemsetAsync(bucket, 0, (size_t)YDIM * MAXM_PER_CLASS * 4, stream);
    hipMemsetAsync(counts, 0, 16 * 32 * 4, stream);

    // prep inputs + buckets (no cross-block same-line atomic serialization)
    prep_x_k<<<B_ROWS / 2, 256, 0, stream>>>(theta, lam, yoh, xb);
    bucket_k<<<B_ROWS / 256, 256, 0, stream>>>(yoh, counts, bucket);

    // weight conversions (transpose to [N][K] bf16)
    tcvt_k<<<dim3(WIDTH / 32, KIN / 32, 1),    256, 0, stream>>>(W_in, WiT, 81,   WIDTH, KIN);
    tcvt_k<<<dim3(HID / 32,   WIDTH / 32, 4),  256, 0, stream>>>(w1,   w1T, WIDTH, HID,  WIDTH);
    tcvt_k<<<dim3(WIDTH / 32, HID / 32, 4),    256, 0, stream>>>(w2,   w2T, HID,  WIDTH, HID);
    tcvt_k<<<dim3(OUTD / 32,  WIDTH / 32, 16), 256, 0, stream>>>(Wh,   WhT, WIDTH, OUTD, WIDTH);

    // input GEMM + GELU -> h fp32
    gemm_k<0><<<(B_ROWS / 128) * (WIDTH / 128), 256, 0, stream>>>(
        (const short*)xb, (const short*)WiT, b_in, h, nullptr,
        nullptr, 0, 0, nullptr, nullptr, nullptr, WIDTH, KIN, WIDTH / 128);

    for (int i = 0; i < NBLK; ++i) {
        ln_k<<<B_ROWS, 256, 0, stream>>>(h, ln_g + i * WIDTH, ln_b + i * WIDTH, z);
        gemm_k<1><<<(B_ROWS / 128) * (HID / 128), 256, 0, stream>>>(
            (const short*)z, (const short*)(w1T + (size_t)i * HID * WIDTH), b1 + i * HID,
            nullptr, t, nullptr, 0, 0, nullptr, nullptr, nullptr, HID, WIDTH, HID / 128);
        gemm_k<2><<<(B_ROWS / 128) * (WIDTH / 128), 256, 0, stream>>>(
            (const short*)t, (const short*)(w2T + (size_t)i * WIDTH * HID), b2 + i * WIDTH,
            h, hb, rsc, i, (i == NBLK - 1) ? 1 : 0, nullptr, nullptr, nullptr,
            WIDTH, HID, WIDTH / 128);
    }

    // bucketed head GEMM
    gemm_k<3><<<dim3(OUTD / 128, MAXM_PER_CLASS / 128, YDIM), 256, 0, stream>>>(
        (const short*)hb, (const short*)WhT, bh, nullptr, nullptr,
        nullptr, 0, 0, counts, bucket, out, OUTD, WIDTH, OUTD / 128);

    (void)in_sizes; (void)n_in; (void)out_size; (void)ws_size; (void)rsc;
}

// Round 4
// 1057.946 us; speedup vs baseline: 1.2314x; 1.0579x over previous
//
#include <hip/hip_runtime.h>
#include <hip/hip_bf16.h>
#include <cstdint>
#include <cstddef>

#define B_ROWS 16384
#define WIDTH  1024
#define HID    2048
#define NBLK   4
#define YDIM   16
#define OUTD   256
#define KIN    128          // input dim 81 padded to 128
#define MAXM_PER_CLASS 4096

typedef __attribute__((ext_vector_type(8))) short short8;
typedef __attribute__((ext_vector_type(4))) float f32x4;

__device__ __forceinline__ unsigned short f2bf(float f) {
    union { float f; uint32_t u; } v; v.f = f;
    uint32_t u = v.u;
    uint32_t r = (u + 0x7FFFu + ((u >> 16) & 1u)) >> 16;
    return (unsigned short)r;
}

__device__ __forceinline__ void gload_lds16(const void* g, void* l) {
    __builtin_amdgcn_global_load_lds(
        (const __attribute__((address_space(1))) void*)g,
        (__attribute__((address_space(3))) void*)l, 16, 0, 0);
}

// ---------------------------------------------------------------------------
// x build only (no atomics): padded bf16 rows [B,128] = [theta|lambda|y_oh|0]
__global__ __launch_bounds__(256)
void prep_x_k(const float* __restrict__ theta, const float* __restrict__ lam,
              const float* __restrict__ yoh, unsigned short* __restrict__ xb)
{
    int tid = threadIdx.x;
    int row = blockIdx.x * 2 + (tid >> 7);
    int j = tid & 127;
    float v;
    if (j < 64)       v = theta[(size_t)row * 64 + j];
    else if (j == 64) v = lam[row];
    else if (j < 81)  v = yoh[(size_t)row * 16 + (j - 65)];
    else              v = 0.f;
    xb[(size_t)row * KIN + j] = f2bf(v);
}

// ---------------------------------------------------------------------------
// argmax-route rows into per-class buckets; LDS-aggregated histogram, one
// global atomic per (block, class) to cache-line-padded counters.
__global__ __launch_bounds__(256)
void bucket_k(const float* __restrict__ yoh, int* __restrict__ counts,
              int* __restrict__ bucket)
{
    __shared__ int cnt_lds[16];
    __shared__ int base_lds[16];
    int tid = threadIdx.x;
    if (tid < 16) cnt_lds[tid] = 0;
    __syncthreads();
    int row = blockIdx.x * 256 + tid;
    const float4* yr = (const float4*)(yoh + (size_t)row * 16);
    int best = 0; float bv = -3.0e38f;
    #pragma unroll
    for (int p = 0; p < 4; ++p) {
        float4 v = yr[p];
        if (v.x > bv) { bv = v.x; best = p * 4 + 0; }
        if (v.y > bv) { bv = v.y; best = p * 4 + 1; }
        if (v.z > bv) { bv = v.z; best = p * 4 + 2; }
        if (v.w > bv) { bv = v.w; best = p * 4 + 3; }
    }
    int mypos = atomicAdd(&cnt_lds[best], 1);
    __syncthreads();
    if (tid < 16) base_lds[tid] = atomicAdd(&counts[tid * 32], cnt_lds[tid]);
    __syncthreads();
    int pos = base_lds[best] + mypos;
    if (pos < MAXM_PER_CLASS) bucket[best * MAXM_PER_CLASS + pos] = row;
}

// ---------------------------------------------------------------------------
// batched transpose + fp32->bf16: src [R][C] -> dst [C][RP], zero-padding rows R..RP
__global__ __launch_bounds__(256)
void tcvt_k(const float* __restrict__ src, unsigned short* __restrict__ dst,
            int R, int C, int RP)
{
    int b = blockIdx.z;
    src += (size_t)b * R * C;
    dst += (size_t)b * C * RP;
    __shared__ float tile[32][33];
    int tx = threadIdx.x & 31, ty = threadIdx.x >> 5;   // 32 x 8
    int c0 = blockIdx.x * 32, r0 = blockIdx.y * 32;
    #pragma unroll
    for (int p = 0; p < 4; ++p) {
        int r = r0 + p * 8 + ty;
        float v = (r < R) ? src[(size_t)r * C + c0 + tx] : 0.f;
        tile[p * 8 + ty][tx] = v;
    }
    __syncthreads();
    #pragma unroll
    for (int p = 0; p < 4; ++p) {
        int c = c0 + p * 8 + ty;
        dst[(size_t)c * RP + r0 + tx] = f2bf(tile[tx][p * 8 + ty]);
    }
}

// ---------------------------------------------------------------------------
// LayerNorm: h fp32 [B,1024] -> z bf16 [B,1024]
__global__ __launch_bounds__(256)
void ln_k(const float* __restrict__ h, const float* __restrict__ g,
          const float* __restrict__ bb, unsigned short* __restrict__ z)
{
    int row = blockIdx.x;
    int t = threadIdx.x;
    const float4 v = ((const float4*)(h + (size_t)row * WIDTH))[t];
    float s  = v.x + v.y + v.z + v.w;
    float s2 = v.x * v.x + v.y * v.y + v.z * v.z + v.w * v.w;
    #pragma unroll
    for (int off = 32; off > 0; off >>= 1) {
        s  += __shfl_down(s, off);
        s2 += __shfl_down(s2, off);
    }
    __shared__ float red[8];
    int wv = t >> 6;
    if ((t & 63) == 0) { red[wv] = s; red[4 + wv] = s2; }
    __syncthreads();
    float st = 0.f, s2t = 0.f;
    #pragma unroll
    for (int i = 0; i < 4; ++i) { st += red[i]; s2t += red[4 + i]; }
    float mu  = st * (1.f / 1024.f);
    float var = s2t * (1.f / 1024.f) - mu * mu;
    float rs  = rsqrtf(var + 1e-5f);
    float4 gg  = ((const float4*)g)[t];
    float4 bbv = ((const float4*)bb)[t];
    ushort4 o;
    o.x = f2bf((v.x - mu) * rs * gg.x + bbv.x);
    o.y = f2bf((v.y - mu) * rs * gg.y + bbv.y);
    o.z = f2bf((v.z - mu) * rs * gg.z + bbv.z);
    o.w = f2bf((v.w - mu) * rs * gg.w + bbv.w);
    ((ushort4*)(z + (size_t)row * WIDTH))[t] = o;
}

// ---------------------------------------------------------------------------
// 128x128x(BK=64) bf16 MFMA GEMM, double-buffered LDS, 2-phase pipeline:
// STAGE(t+1) issued BEFORE compute(t); single vmcnt(0)+s_barrier per K-tile
// AFTER the MFMA cluster (T3-minimum recipe). setprio(1) around MFMA (T5).
// B given transposed [N][K].
// EPI: 0 = +bias, GELU -> Cf (fp32)
//      1 = +bias, SiLU -> Cb (bf16)
//      2 = Cf += rscale*( . + bias); optional Cb = bf16(Cf)
//      3 = bucketed head: gathered A rows, out = . + bias (fp32), masked by count
template<int EPI>
__global__ __launch_bounds__(256)
void gemm_k(const short* __restrict__ A, const short* __restrict__ BT,
            const float* __restrict__ bias,
            float* __restrict__ Cf, unsigned short* __restrict__ Cb,
            const float* __restrict__ rs_ptr, int rs_idx, int writeHb,
            const int* __restrict__ counts, const int* __restrict__ bucket,
            float* __restrict__ outp,
            int N, int K, int ntN)
{
    __shared__ short lsA[2][128 * 64];
    __shared__ short lsB[2][128 * 64];
    __shared__ int rowsLds[128];

    int tid = threadIdx.x;
    int w = tid >> 6, lane = tid & 63;

    int bm = 0, bn = 0, m0 = 0, cnt = 0;
    if (EPI == 3) {
        int cls = blockIdx.z;
        cnt = counts[cls * 32];
        if (cnt > MAXM_PER_CLASS) cnt = MAXM_PER_CLASS;
        m0 = blockIdx.y * 128;
        if (m0 >= cnt) return;                       // uniform exit (before any barrier)
        bn = blockIdx.x;
        if (tid < 128) rowsLds[tid] = bucket[cls * MAXM_PER_CLASS + m0 + tid];
        __syncthreads();
        BT   += (size_t)cls * OUTD * WIDTH;
        bias += cls * OUTD;
    } else {
        int nwg = gridDim.x;
        int wg  = blockIdx.x;
        int cpx = nwg >> 3;                          // grids are %8==0
        int swz = (wg & 7) * cpx + (wg >> 3);        // bijective XCD swizzle
        bm = swz / ntN; bn = swz % ntN;
    }

    const int sr = lane >> 3;    // 0..7
    const int ss = lane & 7;     // 0..7
    const int wm = w >> 1, wn = w & 1;
    const int nkt = K >> 6;

    f32x4 acc[4][4];
    #pragma unroll
    for (int i = 0; i < 4; ++i)
        #pragma unroll
        for (int j = 0; j < 4; ++j) acc[i][j] = (f32x4)(0.f);

    // stage one 128x64 K-tile of A and B into LDS buffer `buf`
    // (XOR-swizzled content via pre-swizzled per-lane global source)
    auto STAGE = [&](int buf, int kt) {
        #pragma unroll
        for (int c = 0; c < 4; ++c) {
            int r  = w * 32 + c * 8 + sr;
            int sg = ss ^ (r & 7);
            long grow = (EPI == 3) ? (long)rowsLds[r] : ((long)bm * 128 + r);
            const short* ga = A + (size_t)grow * K + (size_t)kt * 64 + sg * 8;
            gload_lds16(ga, &lsA[buf][(w * 32 + c * 8) * 64]);
        }
        #pragma unroll
        for (int c = 0; c < 4; ++c) {
            int r  = w * 32 + c * 8 + sr;
            int sg = ss ^ (r & 7);
            const short* gb = BT + (size_t)(bn * 128 + r) * K + (size_t)kt * 64 + sg * 8;
            gload_lds16(gb, &lsB[buf][(w * 32 + c * 8) * 64]);
        }
    };

    // prologue: tile 0 into buf0, drain, barrier
    STAGE(0, 0);
    asm volatile("s_waitcnt vmcnt(0)" ::: "memory");
    __builtin_amdgcn_s_barrier();

    int cur = 0;
    for (int kt = 0; kt < nkt; ++kt) {
        // issue next tile's loads FIRST — they land while we compute tile kt
        if (kt + 1 < nkt) STAGE(cur ^ 1, kt + 1);

        #pragma unroll
        for (int ks = 0; ks < 2; ++ks) {
            short8 af[4], bf[4];
            #pragma unroll
            for (int m = 0; m < 4; ++m) {
                int r = wm * 64 + m * 16 + (lane & 15);
                int s = ks * 4 + (lane >> 4);
                af[m] = *(const short8*)&lsA[cur][r * 64 + (s ^ (r & 7)) * 8];
            }
            #pragma unroll
            for (int n = 0; n < 4; ++n) {
                int r = wn * 64 + n * 16 + (lane & 15);
                int s = ks * 4 + (lane >> 4);
                bf[n] = *(const short8*)&lsB[cur][r * 64 + (s ^ (r & 7)) * 8];
            }
            __builtin_amdgcn_s_setprio(1);
            #pragma unroll
            for (int m = 0; m < 4; ++m)
                #pragma unroll
                for (int n = 0; n < 4; ++n)
                    acc[m][n] = __builtin_amdgcn_mfma_f32_16x16x32_bf16(af[m], bf[n], acc[m][n], 0, 0, 0);
            __builtin_amdgcn_s_setprio(0);
        }

        // next tile landed + all waves done reading buf[cur] -> safe to proceed
        asm volatile("s_waitcnt vmcnt(0)" ::: "memory");
        __builtin_amdgcn_s_barrier();
        cur ^= 1;
    }

    float rscale = (EPI == 2) ? rs_ptr[rs_idx] : 0.f;
    #pragma unroll
    for (int m = 0; m < 4; ++m) {
        #pragma unroll
        for (int reg = 0; reg < 4; ++reg) {
            int lr = wm * 64 + m * 16 + (lane >> 4) * 4 + reg;
            #pragma unroll
            for (int n = 0; n < 4; ++n) {
                int lc = wn * 64 + n * 16 + (lane & 15);
                float v = acc[m][n][reg];
                if (EPI == 0) {
                    size_t idx = ((size_t)bm * 128 + lr) * (size_t)N + bn * 128 + lc;
                    float x = v + bias[bn * 128 + lc];
                    Cf[idx] = 0.5f * x * (1.f + erff(x * 0.70710678118f));
                } else if (EPI == 1) {
                    size_t idx = ((size_t)bm * 128 + lr) * (size_t)N + bn * 128 + lc;
                    float x = v + bias[bn * 128 + lc];
                    Cb[idx] = f2bf(x / (1.f + __expf(-x)));
                } else if (EPI == 2) {
                    size_t idx = ((size_t)bm * 128 + lr) * (size_t)N + bn * 128 + lc;
                    float x = v + bias[bn * 128 + lc];
                    float hv = Cf[idx] + rscale * x;
                    Cf[idx] = hv;
                    if (writeHb) Cb[idx] = f2bf(hv);
                } else {
                    if (m0 + lr < cnt) {
                        int orow = rowsLds[lr];
                        int oc = bn * 128 + lc;
                        outp[(size_t)orow * OUTD + oc] = v + bias[oc];
                    }
                }
            }
        }
    }
}

// ---------------------------------------------------------------------------
extern "C" void kernel_launch(void* const* d_in, const int* in_sizes, int n_in,
                              void* d_out, int out_size, void* d_ws, size_t ws_size,
                              hipStream_t stream)
{
    const float* theta = (const float*)d_in[0];
    const float* lam   = (const float*)d_in[1];
    const float* yoh   = (const float*)d_in[2];
    const float* W_in  = (const float*)d_in[3];
    const float* b_in  = (const float*)d_in[4];
    const float* ln_g  = (const float*)d_in[5];
    const float* ln_b  = (const float*)d_in[6];
    const float* w1    = (const float*)d_in[7];
    const float* b1    = (const float*)d_in[8];
    const float* w2    = (const float*)d_in[9];
    const float* b2    = (const float*)d_in[10];
    const float* rsc   = (const float*)d_in[11];
    const float* Wh    = (const float*)d_in[12];
    const float* bh    = (const float*)d_in[13];
    float* out = (float*)d_out;

    char* p = (char*)d_ws;
    auto alloc = [&](size_t bytes) -> char* {
        char* r = p; p += (bytes + 255) & ~(size_t)255; return r;
    };
    float*          h    = (float*)         alloc((size_t)B_ROWS * WIDTH * 4);
    unsigned short* hb   = (unsigned short*)alloc((size_t)B_ROWS * WIDTH * 2);
    unsigned short* z    = (unsigned short*)alloc((size_t)B_ROWS * WIDTH * 2);
    unsigned short* t    = (unsigned short*)alloc((size_t)B_ROWS * HID * 2);
    unsigned short* xb   = (unsigned short*)alloc((size_t)B_ROWS * KIN * 2);
    unsigned short* w1T  = (unsigned short*)alloc((size_t)NBLK * HID * WIDTH * 2);
    unsigned short* w2T  = (unsigned short*)alloc((size_t)NBLK * WIDTH * HID * 2);
    unsigned short* WhT  = (unsigned short*)alloc((size_t)YDIM * OUTD * WIDTH * 2);
    unsigned short* WiT  = (unsigned short*)alloc((size_t)WIDTH * KIN * 2);
    int*            bucket = (int*)alloc((size_t)YDIM * MAXM_PER_CLASS * 4);
    int*            counts = (int*)alloc(16 * 32 * 4);

    hipMemsetAsync(bucket, 0, (size_t)YDIM * MAXM_PER_CLASS * 4, stream);
    hipMemsetAsync(counts, 0, 16 * 32 * 4, stream);

    // prep inputs + buckets (no cross-block same-line atomic serialization)
    prep_x_k<<<B_ROWS / 2, 256, 0, stream>>>(theta, lam, yoh, xb);
    bucket_k<<<B_ROWS / 256, 256, 0, stream>>>(yoh, counts, bucket);

    // weight conversions (transpose to [N][K] bf16)
    tcvt_k<<<dim3(WIDTH / 32, KIN / 32, 1),    256, 0, stream>>>(W_in, WiT, 81,   WIDTH, KIN);
    tcvt_k<<<dim3(HID / 32,   WIDTH / 32, 4),  256, 0, stream>>>(w1,   w1T, WIDTH, HID,  WIDTH);
    tcvt_k<<<dim3(WIDTH / 32, HID / 32, 4),    256, 0, stream>>>(w2,   w2T, HID,  WIDTH, HID);
    tcvt_k<<<dim3(OUTD / 32,  WIDTH / 32, 16), 256, 0, stream>>>(Wh,   WhT, WIDTH, OUTD, WIDTH);

    // input GEMM + GELU -> h fp32
    gemm_k<0><<<(B_ROWS / 128) * (WIDTH / 128), 256, 0, stream>>>(
        (const short*)xb, (const short*)WiT, b_in, h, nullptr,
        nullptr, 0, 0, nullptr, nullptr, nullptr, WIDTH, KIN, WIDTH / 128);

    for (int i = 0; i < NBLK; ++i) {
        ln_k<<<B_ROWS, 256, 0, stream>>>(h, ln_g + i * WIDTH, ln_b + i * WIDTH, z);
        gemm_k<1><<<(B_ROWS / 128) * (HID / 128), 256, 0, stream>>>(
            (const short*)z, (const short*)(w1T + (size_t)i * HID * WIDTH), b1 + i * HID,
            nullptr, t, nullptr, 0, 0, nullptr, nullptr, nullptr, HID, WIDTH, HID / 128);
        gemm_k<2><<<(B_ROWS / 128) * (WIDTH / 128), 256, 0, stream>>>(
            (const short*)t, (const short*)(w2T + (size_t)i * WIDTH * HID), b2 + i * WIDTH,
            h, hb, rsc, i, (i == NBLK - 1) ? 1 : 0, nullptr, nullptr, nullptr,
            WIDTH, HID, WIDTH / 128);
    }

    // bucketed head GEMM
    gemm_k<3><<<dim3(OUTD / 128, MAXM_PER_CLASS / 128, YDIM), 256, 0, stream>>>(
        (const short*)hb, (const short*)WhT, bh, nullptr, nullptr,
        nullptr, 0, 0, counts, bucket, out, OUTD, WIDTH, OUTD / 128);

    (void)in_sizes; (void)n_in; (void)out_size; (void)ws_size; (void)rsc;
}

// Round 5
// 1012.771 us; speedup vs baseline: 1.2864x; 1.0446x over previous
//
#include <hip/hip_runtime.h>
#include <hip/hip_bf16.h>
#include <cstdint>
#include <cstddef>

#define B_ROWS 16384
#define WIDTH  1024
#define HID    2048
#define NBLK   4
#define YDIM   16
#define OUTD   256
#define KIN    128          // input dim 81 padded to 128
#define MAXM_PER_CLASS 4096

typedef __attribute__((ext_vector_type(8))) short short8;
typedef __attribute__((ext_vector_type(4))) float f32x4;

__device__ __forceinline__ unsigned short f2bf(float f) {
    union { float f; uint32_t u; } v; v.f = f;
    uint32_t u = v.u;
    uint32_t r = (u + 0x7FFFu + ((u >> 16) & 1u)) >> 16;
    return (unsigned short)r;
}

__device__ __forceinline__ void gload_lds16(const void* g, void* l) {
    __builtin_amdgcn_global_load_lds(
        (const __attribute__((address_space(1))) void*)g,
        (__attribute__((address_space(3))) void*)l, 16, 0, 0);
}

// ---------------------------------------------------------------------------
// x build only (no atomics): padded bf16 rows [B,128] = [theta|lambda|y_oh|0]
__global__ __launch_bounds__(256)
void prep_x_k(const float* __restrict__ theta, const float* __restrict__ lam,
              const float* __restrict__ yoh, unsigned short* __restrict__ xb)
{
    int tid = threadIdx.x;
    int row = blockIdx.x * 2 + (tid >> 7);
    int j = tid & 127;
    float v;
    if (j < 64)       v = theta[(size_t)row * 64 + j];
    else if (j == 64) v = lam[row];
    else if (j < 81)  v = yoh[(size_t)row * 16 + (j - 65)];
    else              v = 0.f;
    xb[(size_t)row * KIN + j] = f2bf(v);
}

// ---------------------------------------------------------------------------
// argmax-route rows into per-class buckets; LDS-aggregated histogram, one
// global atomic per (block, class) to cache-line-padded counters.
__global__ __launch_bounds__(256)
void bucket_k(const float* __restrict__ yoh, int* __restrict__ counts,
              int* __restrict__ bucket)
{
    __shared__ int cnt_lds[16];
    __shared__ int base_lds[16];
    int tid = threadIdx.x;
    if (tid < 16) cnt_lds[tid] = 0;
    __syncthreads();
    int row = blockIdx.x * 256 + tid;
    const float4* yr = (const float4*)(yoh + (size_t)row * 16);
    int best = 0; float bv = -3.0e38f;
    #pragma unroll
    for (int p = 0; p < 4; ++p) {
        float4 v = yr[p];
        if (v.x > bv) { bv = v.x; best = p * 4 + 0; }
        if (v.y > bv) { bv = v.y; best = p * 4 + 1; }
        if (v.z > bv) { bv = v.z; best = p * 4 + 2; }
        if (v.w > bv) { bv = v.w; best = p * 4 + 3; }
    }
    int mypos = atomicAdd(&cnt_lds[best], 1);
    __syncthreads();
    if (tid < 16) base_lds[tid] = atomicAdd(&counts[tid * 32], cnt_lds[tid]);
    __syncthreads();
    int pos = base_lds[best] + mypos;
    if (pos < MAXM_PER_CLASS) bucket[best * MAXM_PER_CLASS + pos] = row;
}

// ---------------------------------------------------------------------------
// batched transpose + fp32->bf16: src [R][C] -> dst [C][RP], zero-padding rows R..RP
__global__ __launch_bounds__(256)
void tcvt_k(const float* __restrict__ src, unsigned short* __restrict__ dst,
            int R, int C, int RP)
{
    int b = blockIdx.z;
    src += (size_t)b * R * C;
    dst += (size_t)b * C * RP;
    __shared__ float tile[32][33];
    int tx = threadIdx.x & 31, ty = threadIdx.x >> 5;   // 32 x 8
    int c0 = blockIdx.x * 32, r0 = blockIdx.y * 32;
    #pragma unroll
    for (int p = 0; p < 4; ++p) {
        int r = r0 + p * 8 + ty;
        float v = (r < R) ? src[(size_t)r * C + c0 + tx] : 0.f;
        tile[p * 8 + ty][tx] = v;
    }
    __syncthreads();
    #pragma unroll
    for (int p = 0; p < 4; ++p) {
        int c = c0 + p * 8 + ty;
        dst[(size_t)c * RP + r0 + tx] = f2bf(tile[tx][p * 8 + ty]);
    }
}

// ---------------------------------------------------------------------------
// LayerNorm: h fp32 [B,1024] -> z bf16 [B,1024]
__global__ __launch_bounds__(256)
void ln_k(const float* __restrict__ h, const float* __restrict__ g,
          const float* __restrict__ bb, unsigned short* __restrict__ z)
{
    int row = blockIdx.x;
    int t = threadIdx.x;
    const float4 v = ((const float4*)(h + (size_t)row * WIDTH))[t];
    float s  = v.x + v.y + v.z + v.w;
    float s2 = v.x * v.x + v.y * v.y + v.z * v.z + v.w * v.w;
    #pragma unroll
    for (int off = 32; off > 0; off >>= 1) {
        s  += __shfl_down(s, off);
        s2 += __shfl_down(s2, off);
    }
    __shared__ float red[8];
    int wv = t >> 6;
    if ((t & 63) == 0) { red[wv] = s; red[4 + wv] = s2; }
    __syncthreads();
    float st = 0.f, s2t = 0.f;
    #pragma unroll
    for (int i = 0; i < 4; ++i) { st += red[i]; s2t += red[4 + i]; }
    float mu  = st * (1.f / 1024.f);
    float var = s2t * (1.f / 1024.f) - mu * mu;
    float rs  = rsqrtf(var + 1e-5f);
    float4 gg  = ((const float4*)g)[t];
    float4 bbv = ((const float4*)bb)[t];
    ushort4 o;
    o.x = f2bf((v.x - mu) * rs * gg.x + bbv.x);
    o.y = f2bf((v.y - mu) * rs * gg.y + bbv.y);
    o.z = f2bf((v.z - mu) * rs * gg.z + bbv.z);
    o.w = f2bf((v.w - mu) * rs * gg.w + bbv.w);
    ((ushort4*)(z + (size_t)row * WIDTH))[t] = o;
}

// ---------------------------------------------------------------------------
// 256x256x(BK=64) bf16 MFMA GEMM, 512 threads (8 waves, 2M x 4N), 128 KiB LDS
// double buffer, 2-phase pipeline: STAGE(t+1) before compute(t), one
// vmcnt(0)+s_barrier per K-tile after the MFMA cluster. setprio around MFMA.
// Per wave: 128x64 output = acc[8][4] f32x4.
// EPI: 1 = +bias, SiLU -> Cb (bf16)
//      2 = Cf += rscale*( . + bias); optional Cb = bf16(Cf)
template<int EPI>
__global__ __launch_bounds__(512, 2)
void gemm256_k(const short* __restrict__ A, const short* __restrict__ BT,
               const float* __restrict__ bias,
               float* __restrict__ Cf, unsigned short* __restrict__ Cb,
               const float* __restrict__ rs_ptr, int rs_idx, int writeHb,
               int N, int K, int ntN)
{
    __shared__ short lsA[2][256 * 64];
    __shared__ short lsB[2][256 * 64];

    int tid = threadIdx.x;
    int w = tid >> 6, lane = tid & 63;

    int nwg = gridDim.x;
    int wg  = blockIdx.x;
    int cpx = nwg >> 3;                          // grids are %8==0
    int swz = (wg & 7) * cpx + (wg >> 3);        // bijective XCD swizzle
    int bm = swz / ntN, bn = swz % ntN;

    const int wm = w >> 2, wn = w & 3;           // wave position: 2M x 4N
    const int lr8 = lane >> 3;                   // 0..7 (row within 8-row group)
    const int ls8 = lane & 7;                    // 0..7 (16B slot within row)
    const int nkt = K >> 6;

    f32x4 acc[8][4];
    #pragma unroll
    for (int i = 0; i < 8; ++i)
        #pragma unroll
        for (int j = 0; j < 4; ++j) acc[i][j] = (f32x4)(0.f);

    // stage one 256x64 K-tile of A and B into LDS buffer `buf`
    // (XOR-swizzled content via pre-swizzled per-lane global source;
    //  LDS dest is wave-uniform base + lane*16 as gload_lds requires)
    auto STAGE = [&](int buf, int kt) {
        #pragma unroll
        for (int c = 0; c < 4; ++c) {
            int r  = c * 64 + w * 8 + lr8;
            int sg = ls8 ^ (r & 7);
            const short* ga = A + (size_t)(bm * 256 + r) * K + (size_t)kt * 64 + sg * 8;
            gload_lds16(ga, &lsA[buf][(c * 64 + w * 8) * 64]);
        }
        #pragma unroll
        for (int c = 0; c < 4; ++c) {
            int r  = c * 64 + w * 8 + lr8;
            int sg = ls8 ^ (r & 7);
            const short* gb = BT + (size_t)(bn * 256 + r) * K + (size_t)kt * 64 + sg * 8;
            gload_lds16(gb, &lsB[buf][(c * 64 + w * 8) * 64]);
        }
    };

    STAGE(0, 0);
    asm volatile("s_waitcnt vmcnt(0)" ::: "memory");
    __builtin_amdgcn_s_barrier();

    int cur = 0;
    for (int kt = 0; kt < nkt; ++kt) {
        if (kt + 1 < nkt) STAGE(cur ^ 1, kt + 1);

        #pragma unroll
        for (int ks = 0; ks < 2; ++ks) {
            short8 af[8], bf[4];
            int s = ks * 4 + (lane >> 4);
            #pragma unroll
            for (int m = 0; m < 8; ++m) {
                int r = wm * 128 + m * 16 + (lane & 15);
                af[m] = *(const short8*)&lsA[cur][r * 64 + (s ^ (r & 7)) * 8];
            }
            #pragma unroll
            for (int n = 0; n < 4; ++n) {
                int r = wn * 64 + n * 16 + (lane & 15);
                bf[n] = *(const short8*)&lsB[cur][r * 64 + (s ^ (r & 7)) * 8];
            }
            __builtin_amdgcn_s_setprio(1);
            #pragma unroll
            for (int m = 0; m < 8; ++m)
                #pragma unroll
                for (int n = 0; n < 4; ++n)
                    acc[m][n] = __builtin_amdgcn_mfma_f32_16x16x32_bf16(af[m], bf[n], acc[m][n], 0, 0, 0);
            __builtin_amdgcn_s_setprio(0);
        }

        asm volatile("s_waitcnt vmcnt(0)" ::: "memory");
        __builtin_amdgcn_s_barrier();
        cur ^= 1;
    }

    float rscale = (EPI == 2) ? rs_ptr[rs_idx] : 0.f;
    #pragma unroll
    for (int m = 0; m < 8; ++m) {
        #pragma unroll
        for (int reg = 0; reg < 4; ++reg) {
            int lr = wm * 128 + m * 16 + (lane >> 4) * 4 + reg;
            #pragma unroll
            for (int n = 0; n < 4; ++n) {
                int lc = wn * 64 + n * 16 + (lane & 15);
                float v = acc[m][n][reg];
                size_t idx = ((size_t)bm * 256 + lr) * (size_t)N + bn * 256 + lc;
                float x = v + bias[bn * 256 + lc];
                if (EPI == 1) {
                    Cb[idx] = f2bf(x / (1.f + __expf(-x)));
                } else {
                    float hv = Cf[idx] + rscale * x;
                    Cf[idx] = hv;
                    if (writeHb) Cb[idx] = f2bf(hv);
                }
            }
        }
    }
}

// ---------------------------------------------------------------------------
// 128x128x(BK=64) bf16 MFMA GEMM (kept for small shapes), double-buffered,
// 2-phase pipeline. B given transposed [N][K].
// EPI: 0 = +bias, GELU -> Cf (fp32)
//      3 = bucketed head: gathered A rows, out = . + bias (fp32), masked by count
template<int EPI>
__global__ __launch_bounds__(256)
void gemm_k(const short* __restrict__ A, const short* __restrict__ BT,
            const float* __restrict__ bias,
            float* __restrict__ Cf,
            const int* __restrict__ counts, const int* __restrict__ bucket,
            float* __restrict__ outp,
            int N, int K, int ntN)
{
    __shared__ short lsA[2][128 * 64];
    __shared__ short lsB[2][128 * 64];
    __shared__ int rowsLds[128];

    int tid = threadIdx.x;
    int w = tid >> 6, lane = tid & 63;

    int bm = 0, bn = 0, m0 = 0, cnt = 0;
    if (EPI == 3) {
        int cls = blockIdx.z;
        cnt = counts[cls * 32];
        if (cnt > MAXM_PER_CLASS) cnt = MAXM_PER_CLASS;
        m0 = blockIdx.y * 128;
        if (m0 >= cnt) return;                       // uniform exit (before any barrier)
        bn = blockIdx.x;
        if (tid < 128) rowsLds[tid] = bucket[cls * MAXM_PER_CLASS + m0 + tid];
        __syncthreads();
        BT   += (size_t)cls * OUTD * WIDTH;
        bias += cls * OUTD;
    } else {
        int nwg = gridDim.x;
        int wg  = blockIdx.x;
        int cpx = nwg >> 3;                          // grids are %8==0
        int swz = (wg & 7) * cpx + (wg >> 3);        // bijective XCD swizzle
        bm = swz / ntN; bn = swz % ntN;
    }

    const int sr = lane >> 3;    // 0..7
    const int ss = lane & 7;     // 0..7
    const int wm = w >> 1, wn = w & 1;
    const int nkt = K >> 6;

    f32x4 acc[4][4];
    #pragma unroll
    for (int i = 0; i < 4; ++i)
        #pragma unroll
        for (int j = 0; j < 4; ++j) acc[i][j] = (f32x4)(0.f);

    auto STAGE = [&](int buf, int kt) {
        #pragma unroll
        for (int c = 0; c < 4; ++c) {
            int r  = w * 32 + c * 8 + sr;
            int sg = ss ^ (r & 7);
            long grow = (EPI == 3) ? (long)rowsLds[r] : ((long)bm * 128 + r);
            const short* ga = A + (size_t)grow * K + (size_t)kt * 64 + sg * 8;
            gload_lds16(ga, &lsA[buf][(w * 32 + c * 8) * 64]);
        }
        #pragma unroll
        for (int c = 0; c < 4; ++c) {
            int r  = w * 32 + c * 8 + sr;
            int sg = ss ^ (r & 7);
            const short* gb = BT + (size_t)(bn * 128 + r) * K + (size_t)kt * 64 + sg * 8;
            gload_lds16(gb, &lsB[buf][(w * 32 + c * 8) * 64]);
        }
    };

    STAGE(0, 0);
    asm volatile("s_waitcnt vmcnt(0)" ::: "memory");
    __builtin_amdgcn_s_barrier();

    int cur = 0;
    for (int kt = 0; kt < nkt; ++kt) {
        if (kt + 1 < nkt) STAGE(cur ^ 1, kt + 1);

        #pragma unroll
        for (int ks = 0; ks < 2; ++ks) {
            short8 af[4], bf[4];
            #pragma unroll
            for (int m = 0; m < 4; ++m) {
                int r = wm * 64 + m * 16 + (lane & 15);
                int s = ks * 4 + (lane >> 4);
                af[m] = *(const short8*)&lsA[cur][r * 64 + (s ^ (r & 7)) * 8];
            }
            #pragma unroll
            for (int n = 0; n < 4; ++n) {
                int r = wn * 64 + n * 16 + (lane & 15);
                int s = ks * 4 + (lane >> 4);
                bf[n] = *(const short8*)&lsB[cur][r * 64 + (s ^ (r & 7)) * 8];
            }
            __builtin_amdgcn_s_setprio(1);
            #pragma unroll
            for (int m = 0; m < 4; ++m)
                #pragma unroll
                for (int n = 0; n < 4; ++n)
                    acc[m][n] = __builtin_amdgcn_mfma_f32_16x16x32_bf16(af[m], bf[n], acc[m][n], 0, 0, 0);
            __builtin_amdgcn_s_setprio(0);
        }

        asm volatile("s_waitcnt vmcnt(0)" ::: "memory");
        __builtin_amdgcn_s_barrier();
        cur ^= 1;
    }

    #pragma unroll
    for (int m = 0; m < 4; ++m) {
        #pragma unroll
        for (int reg = 0; reg < 4; ++reg) {
            int lr = wm * 64 + m * 16 + (lane >> 4) * 4 + reg;
            #pragma unroll
            for (int n = 0; n < 4; ++n) {
                int lc = wn * 64 + n * 16 + (lane & 15);
                float v = acc[m][n][reg];
                if (EPI == 0) {
                    size_t idx = ((size_t)bm * 128 + lr) * (size_t)N + bn * 128 + lc;
                    float x = v + bias[bn * 128 + lc];
                    Cf[idx] = 0.5f * x * (1.f + erff(x * 0.70710678118f));
                } else {
                    if (m0 + lr < cnt) {
                        int orow = rowsLds[lr];
                        int oc = bn * 128 + lc;
                        outp[(size_t)orow * OUTD + oc] = v + bias[oc];
                    }
                }
            }
        }
    }
}

// ---------------------------------------------------------------------------
extern "C" void kernel_launch(void* const* d_in, const int* in_sizes, int n_in,
                              void* d_out, int out_size, void* d_ws, size_t ws_size,
                              hipStream_t stream)
{
    const float* theta = (const float*)d_in[0];
    const float* lam   = (const float*)d_in[1];
    const float* yoh   = (const float*)d_in[2];
    const float* W_in  = (const float*)d_in[3];
    const float* b_in  = (const float*)d_in[4];
    const float* ln_g  = (const float*)d_in[5];
    const float* ln_b  = (const float*)d_in[6];
    const float* w1    = (const float*)d_in[7];
    const float* b1    = (const float*)d_in[8];
    const float* w2    = (const float*)d_in[9];
    const float* b2    = (const float*)d_in[10];
    const float* rsc   = (const float*)d_in[11];
    const float* Wh    = (const float*)d_in[12];
    const float* bh    = (const float*)d_in[13];
    float* out = (float*)d_out;

    char* p = (char*)d_ws;
    auto alloc = [&](size_t bytes) -> char* {
        char* r = p; p += (bytes + 255) & ~(size_t)255; return r;
    };
    float*          h    = (float*)         alloc((size_t)B_ROWS * WIDTH * 4);
    unsigned short* hb   = (unsigned short*)alloc((size_t)B_ROWS * WIDTH * 2);
    unsigned short* z    = (unsigned short*)alloc((size_t)B_ROWS * WIDTH * 2);
    unsigned short* t    = (unsigned short*)alloc((size_t)B_ROWS * HID * 2);
    unsigned short* xb   = (unsigned short*)alloc((size_t)B_ROWS * KIN * 2);
    unsigned short* w1T  = (unsigned short*)alloc((size_t)NBLK * HID * WIDTH * 2);
    unsigned short* w2T  = (unsigned short*)alloc((size_t)NBLK * WIDTH * HID * 2);
    unsigned short* WhT  = (unsigned short*)alloc((size_t)YDIM * OUTD * WIDTH * 2);
    unsigned short* WiT  = (unsigned short*)alloc((size_t)WIDTH * KIN * 2);
    int*            bucket = (int*)alloc((size_t)YDIM * MAXM_PER_CLASS * 4);
    int*            counts = (int*)alloc(16 * 32 * 4);

    hipMemsetAsync(bucket, 0, (size_t)YDIM * MAXM_PER_CLASS * 4, stream);
    hipMemsetAsync(counts, 0, 16 * 32 * 4, stream);

    // prep inputs + buckets (no cross-block same-line atomic serialization)
    prep_x_k<<<B_ROWS / 2, 256, 0, stream>>>(theta, lam, yoh, xb);
    bucket_k<<<B_ROWS / 256, 256, 0, stream>>>(yoh, counts, bucket);

    // weight conversions (transpose to [N][K] bf16)
    tcvt_k<<<dim3(WIDTH / 32, KIN / 32, 1),    256, 0, stream>>>(W_in, WiT, 81,   WIDTH, KIN);
    tcvt_k<<<dim3(HID / 32,   WIDTH / 32, 4),  256, 0, stream>>>(w1,   w1T, WIDTH, HID,  WIDTH);
    tcvt_k<<<dim3(WIDTH / 32, HID / 32, 4),    256, 0, stream>>>(w2,   w2T, HID,  WIDTH, HID);
    tcvt_k<<<dim3(OUTD / 32,  WIDTH / 32, 16), 256, 0, stream>>>(Wh,   WhT, WIDTH, OUTD, WIDTH);

    // input GEMM + GELU -> h fp32 (128^2 kernel; K=128 is too small for 256^2)
    gemm_k<0><<<(B_ROWS / 128) * (WIDTH / 128), 256, 0, stream>>>(
        (const short*)xb, (const short*)WiT, b_in, h,
        nullptr, nullptr, nullptr, WIDTH, KIN, WIDTH / 128);

    for (int i = 0; i < NBLK; ++i) {
        ln_k<<<B_ROWS, 256, 0, stream>>>(h, ln_g + i * WIDTH, ln_b + i * WIDTH, z);
        gemm256_k<1><<<(B_ROWS / 256) * (HID / 256), 512, 0, stream>>>(
            (const short*)z, (const short*)(w1T + (size_t)i * HID * WIDTH), b1 + i * HID,
            nullptr, t, nullptr, 0, 0, HID, WIDTH, HID / 256);
        gemm256_k<2><<<(B_ROWS / 256) * (WIDTH / 256), 512, 0, stream>>>(
            (const short*)t, (const short*)(w2T + (size_t)i * WIDTH * HID), b2 + i * WIDTH,
            h, hb, rsc, i, (i == NBLK - 1) ? 1 : 0, WIDTH, HID, WIDTH / 256);
    }

    // bucketed head GEMM (128^2 kernel: per-class M can be small)
    gemm_k<3><<<dim3(OUTD / 128, MAXM_PER_CLASS / 128, YDIM), 256, 0, stream>>>(
        (const short*)hb, (const short*)WhT, bh, nullptr,
        counts, bucket, out, OUTD, WIDTH, OUTD / 128);

    (void)in_sizes; (void)n_in; (void)out_size; (void)ws_size; (void)rsc;
}

// Round 6
// 988.677 us; speedup vs baseline: 1.3177x; 1.0244x over previous
//
#include <hip/hip_runtime.h>
#include <hip/hip_bf16.h>
#include <cstdint>
#include <cstddef>

#define B_ROWS 16384
#define WIDTH  1024
#define HID    2048
#define NBLK   4
#define YDIM   16
#define OUTD   256
#define KIN    128          // input dim 81 padded to 128
#define MAXM_PER_CLASS 4096

typedef __attribute__((ext_vector_type(8))) short short8;
typedef __attribute__((ext_vector_type(4))) float f32x4;

#define FENCE() asm volatile("" ::: "memory")
#define BAR()   do { FENCE(); __builtin_amdgcn_s_barrier(); FENCE(); } while (0)
#define LGKM0() asm volatile("s_waitcnt lgkmcnt(0)" ::: "memory")
#define VM4()   asm volatile("s_waitcnt vmcnt(4)" ::: "memory")
#define VM0()   asm volatile("s_waitcnt vmcnt(0)" ::: "memory")

__device__ __forceinline__ unsigned short f2bf(float f) {
    union { float f; uint32_t u; } v; v.f = f;
    uint32_t u = v.u;
    uint32_t r = (u + 0x7FFFu + ((u >> 16) & 1u)) >> 16;
    return (unsigned short)r;
}

__device__ __forceinline__ void gload_lds16(const void* g, void* l) {
    __builtin_amdgcn_global_load_lds(
        (const __attribute__((address_space(1))) void*)g,
        (__attribute__((address_space(3))) void*)l, 16, 0, 0);
}

// ---------------------------------------------------------------------------
// x build only (no atomics): padded bf16 rows [B,128] = [theta|lambda|y_oh|0]
__global__ __launch_bounds__(256)
void prep_x_k(const float* __restrict__ theta, const float* __restrict__ lam,
              const float* __restrict__ yoh, unsigned short* __restrict__ xb)
{
    int tid = threadIdx.x;
    int row = blockIdx.x * 2 + (tid >> 7);
    int j = tid & 127;
    float v;
    if (j < 64)       v = theta[(size_t)row * 64 + j];
    else if (j == 64) v = lam[row];
    else if (j < 81)  v = yoh[(size_t)row * 16 + (j - 65)];
    else              v = 0.f;
    xb[(size_t)row * KIN + j] = f2bf(v);
}

// ---------------------------------------------------------------------------
// argmax-route rows into per-class buckets; LDS-aggregated histogram, one
// global atomic per (block, class) to cache-line-padded counters.
__global__ __launch_bounds__(256)
void bucket_k(const float* __restrict__ yoh, int* __restrict__ counts,
              int* __restrict__ bucket)
{
    __shared__ int cnt_lds[16];
    __shared__ int base_lds[16];
    int tid = threadIdx.x;
    if (tid < 16) cnt_lds[tid] = 0;
    __syncthreads();
    int row = blockIdx.x * 256 + tid;
    const float4* yr = (const float4*)(yoh + (size_t)row * 16);
    int best = 0; float bv = -3.0e38f;
    #pragma unroll
    for (int p = 0; p < 4; ++p) {
        float4 v = yr[p];
        if (v.x > bv) { bv = v.x; best = p * 4 + 0; }
        if (v.y > bv) { bv = v.y; best = p * 4 + 1; }
        if (v.z > bv) { bv = v.z; best = p * 4 + 2; }
        if (v.w > bv) { bv = v.w; best = p * 4 + 3; }
    }
    int mypos = atomicAdd(&cnt_lds[best], 1);
    __syncthreads();
    if (tid < 16) base_lds[tid] = atomicAdd(&counts[tid * 32], cnt_lds[tid]);
    __syncthreads();
    int pos = base_lds[best] + mypos;
    if (pos < MAXM_PER_CLASS) bucket[best * MAXM_PER_CLASS + pos] = row;
}

// ---------------------------------------------------------------------------
// batched transpose + fp32->bf16: src [R][C] -> dst [C][RP], zero-padding rows R..RP
__global__ __launch_bounds__(256)
void tcvt_k(const float* __restrict__ src, unsigned short* __restrict__ dst,
            int R, int C, int RP)
{
    int b = blockIdx.z;
    src += (size_t)b * R * C;
    dst += (size_t)b * C * RP;
    __shared__ float tile[32][33];
    int tx = threadIdx.x & 31, ty = threadIdx.x >> 5;   // 32 x 8
    int c0 = blockIdx.x * 32, r0 = blockIdx.y * 32;
    #pragma unroll
    for (int p = 0; p < 4; ++p) {
        int r = r0 + p * 8 + ty;
        float v = (r < R) ? src[(size_t)r * C + c0 + tx] : 0.f;
        tile[p * 8 + ty][tx] = v;
    }
    __syncthreads();
    #pragma unroll
    for (int p = 0; p < 4; ++p) {
        int c = c0 + p * 8 + ty;
        dst[(size_t)c * RP + r0 + tx] = f2bf(tile[tx][p * 8 + ty]);
    }
}

// ---------------------------------------------------------------------------
// LayerNorm: h fp32 [B,1024] -> z bf16 [B,1024]
__global__ __launch_bounds__(256)
void ln_k(const float* __restrict__ h, const float* __restrict__ g,
          const float* __restrict__ bb, unsigned short* __restrict__ z)
{
    int row = blockIdx.x;
    int t = threadIdx.x;
    const float4 v = ((const float4*)(h + (size_t)row * WIDTH))[t];
    float s  = v.x + v.y + v.z + v.w;
    float s2 = v.x * v.x + v.y * v.y + v.z * v.z + v.w * v.w;
    #pragma unroll
    for (int off = 32; off > 0; off >>= 1) {
        s  += __shfl_down(s, off);
        s2 += __shfl_down(s2, off);
    }
    __shared__ float red[8];
    int wv = t >> 6;
    if ((t & 63) == 0) { red[wv] = s; red[4 + wv] = s2; }
    __syncthreads();
    float st = 0.f, s2t = 0.f;
    #pragma unroll
    for (int i = 0; i < 4; ++i) { st += red[i]; s2t += red[4 + i]; }
    float mu  = st * (1.f / 1024.f);
    float var = s2t * (1.f / 1024.f) - mu * mu;
    float rs  = rsqrtf(var + 1e-5f);
    float4 gg  = ((const float4*)g)[t];
    float4 bbv = ((const float4*)bb)[t];
    ushort4 o;
    o.x = f2bf((v.x - mu) * rs * gg.x + bbv.x);
    o.y = f2bf((v.y - mu) * rs * gg.y + bbv.y);
    o.z = f2bf((v.z - mu) * rs * gg.z + bbv.z);
    o.w = f2bf((v.w - mu) * rs * gg.w + bbv.w);
    ((ushort4*)(z + (size_t)row * WIDTH))[t] = o;
}

// ---------------------------------------------------------------------------
// 256x256 bf16 MFMA GEMM, 512 threads (8 waves, 2M x 4N), 8-phase schedule
// (T3+T4): 2 K-tiles (BK=64 each) per iteration, one half-tile (128 rows x 64
// cols, 2 gload_lds/thread) staged per phase, counted vmcnt(4) at phases 4/8
// only (never 0 in steady state), setprio around each 16-MFMA quadrant (T5),
// LDS XOR-swizzle (T2) via pre-swizzled global source + swizzled ds_read.
//
// Stage/consume map per iteration it (E = K-tile 2it in buf0, O = 2it+1 in
// buf1; quadrant order per tile: q00,q01,q10,q11 so B-region dies at phase 2,
// A-region at phase 3 of each tile's 4 phases):
//   P1: stage A(O)-h0   P2: A(O)-h1   P3: B(E+2)-h0   P4: B(E+2)-h1 [VM4]
//   P5: A(E+2)-h0       P6: A(E+2)-h1 P7: B(O+2)-h0   P8: B(O+2)-h1 [VM4]
// Every staged unit is >=4 stage-slots old at its consumption gate, so
// vmcnt(4) (= newest 2 units allowed in flight) guarantees it landed.
// EPI: 1 = +bias, SiLU -> Cb (bf16)
//      2 = Cf += rscale*( . + bias); optional Cb = bf16(Cf)
template<int EPI>
__global__ __launch_bounds__(512, 2)
void gemm256_k(const short* __restrict__ A, const short* __restrict__ BT,
               const float* __restrict__ bias,
               float* __restrict__ Cf, unsigned short* __restrict__ Cb,
               const float* __restrict__ rs_ptr, int rs_idx, int writeHb,
               int N, int K, int ntN)
{
    __shared__ short lsA[2][256 * 64];
    __shared__ short lsB[2][256 * 64];

    int tid = threadIdx.x;
    int w = tid >> 6, lane = tid & 63;

    int nwg = gridDim.x;
    int wg  = blockIdx.x;
    int cpx = nwg >> 3;                          // grids are %8==0
    int swz = (wg & 7) * cpx + (wg >> 3);        // bijective XCD swizzle
    int bm = swz / ntN, bn = swz % ntN;

    const int wm = w >> 2, wn = w & 3;           // wave position: 2M x 4N
    const int lr8 = lane >> 3;                   // 0..7
    const int ls8 = lane & 7;                    // 0..7
    const int nkt = K >> 6;
    const int nit = nkt >> 1;

    f32x4 acc[8][4];
    #pragma unroll
    for (int i = 0; i < 8; ++i)
        #pragma unroll
        for (int j = 0; j < 4; ++j) acc[i][j] = (f32x4)(0.f);

    // stage one half-tile (128 rows x 64 cols) of A or B, 2 gload_lds/thread
    auto STAGE_A = [&](int buf, int h, int kt) {
        #pragma unroll
        for (int c = 0; c < 2; ++c) {
            int r  = h * 128 + c * 64 + w * 8 + lr8;
            int sg = ls8 ^ (r & 7);
            const short* g = A + (size_t)(bm * 256 + r) * K + (size_t)kt * 64 + sg * 8;
            gload_lds16(g, &lsA[buf][(h * 128 + c * 64 + w * 8) * 64]);
        }
    };
    auto STAGE_B = [&](int buf, int h, int kt) {
        #pragma unroll
        for (int c = 0; c < 2; ++c) {
            int r  = h * 128 + c * 64 + w * 8 + lr8;
            int sg = ls8 ^ (r & 7);
            const short* g = BT + (size_t)(bn * 256 + r) * K + (size_t)kt * 64 + sg * 8;
            gload_lds16(g, &lsB[buf][(h * 128 + c * 64 + w * 8) * 64]);
        }
    };

    short8 aL[4][2], aH[4][2], bL[2][2], bH[2][2];

    auto RD_AL = [&](int buf) {
        #pragma unroll
        for (int m = 0; m < 4; ++m)
            #pragma unroll
            for (int ks = 0; ks < 2; ++ks) {
                int r = wm * 128 + m * 16 + (lane & 15);
                int s = ks * 4 + (lane >> 4);
                aL[m][ks] = *(const short8*)&lsA[buf][r * 64 + (s ^ (r & 7)) * 8];
            }
    };
    auto RD_AH = [&](int buf) {
        #pragma unroll
        for (int m = 0; m < 4; ++m)
            #pragma unroll
            for (int ks = 0; ks < 2; ++ks) {
                int r = wm * 128 + 64 + m * 16 + (lane & 15);
                int s = ks * 4 + (lane >> 4);
                aH[m][ks] = *(const short8*)&lsA[buf][r * 64 + (s ^ (r & 7)) * 8];
            }
    };
    auto RD_BL = [&](int buf) {
        #pragma unroll
        for (int n = 0; n < 2; ++n)
            #pragma unroll
            for (int ks = 0; ks < 2; ++ks) {
                int r = wn * 64 + n * 16 + (lane & 15);
                int s = ks * 4 + (lane >> 4);
                bL[n][ks] = *(const short8*)&lsB[buf][r * 64 + (s ^ (r & 7)) * 8];
            }
    };
    auto RD_BH = [&](int buf) {
        #pragma unroll
        for (int n = 0; n < 2; ++n)
            #pragma unroll
            for (int ks = 0; ks < 2; ++ks) {
                int r = wn * 64 + 32 + n * 16 + (lane & 15);
                int s = ks * 4 + (lane >> 4);
                bH[n][ks] = *(const short8*)&lsB[buf][r * 64 + (s ^ (r & 7)) * 8];
            }
    };

    auto MM = [&](short8 (&a)[4][2], short8 (&b)[2][2], int mo, int no) {
        __builtin_amdgcn_s_setprio(1);
        #pragma unroll
        for (int ks = 0; ks < 2; ++ks)
            #pragma unroll
            for (int m = 0; m < 4; ++m)
                #pragma unroll
                for (int n = 0; n < 2; ++n)
                    acc[mo + m][no + n] = __builtin_amdgcn_mfma_f32_16x16x32_bf16(
                        a[m][ks], b[n][ks], acc[mo + m][no + n], 0, 0, 0);
        __builtin_amdgcn_s_setprio(0);
    };

    // prologue: B(K0), A(K0) into buf0; B(K1) into buf1. vmcnt(4) keeps the
    // two newest units (B(K1)) in flight.
    STAGE_B(0, 0, 0); STAGE_B(0, 1, 0);
    STAGE_A(0, 0, 0); STAGE_A(0, 1, 0);
    STAGE_B(1, 0, 1); STAGE_B(1, 1, 1);
    VM4(); BAR();

    for (int it = 0; it < nit; ++it) {
        int T = it * 2;
        bool nl = (it + 1 < nit);
        // ---- K-tile T (buf0) ----
        // P1: q00
        RD_AL(0); RD_BL(0);
        STAGE_A(1, 0, T + 1);
        BAR(); LGKM0();
        MM(aL, bL, 0, 0);
        BAR();
        // P2: q01
        RD_BH(0);
        STAGE_A(1, 1, T + 1);
        BAR(); LGKM0();
        MM(aL, bH, 0, 2);
        BAR();
        // P3: q10
        RD_AH(0);
        if (nl) STAGE_B(0, 0, T + 2);
        BAR(); LGKM0();
        MM(aH, bL, 4, 0);
        BAR();
        // P4: q11  [gate: a(T+1) staged at P1/P2 must be landed for P5]
        if (nl) STAGE_B(0, 1, T + 2);
        BAR(); LGKM0();
        MM(aH, bH, 4, 2);
        if (nl) { VM4(); } else { VM0(); }
        BAR();
        // ---- K-tile T+1 (buf1) ----
        // P5: q00
        RD_AL(1); RD_BL(1);
        if (nl) STAGE_A(0, 0, T + 2);
        BAR(); LGKM0();
        MM(aL, bL, 0, 0);
        BAR();
        // P6: q01
        RD_BH(1);
        if (nl) STAGE_A(0, 1, T + 2);
        BAR(); LGKM0();
        MM(aL, bH, 0, 2);
        BAR();
        // P7: q10
        RD_AH(1);
        if (nl) STAGE_B(1, 0, T + 3);
        BAR(); LGKM0();
        MM(aH, bL, 4, 0);
        BAR();
        // P8: q11  [gate: buf0 units staged P3-P6 must be landed for next P1]
        if (nl) STAGE_B(1, 1, T + 3);
        BAR(); LGKM0();
        MM(aH, bH, 4, 2);
        if (nl) { VM4(); }
        BAR();
    }

    float rscale = (EPI == 2) ? rs_ptr[rs_idx] : 0.f;
    #pragma unroll
    for (int m = 0; m < 8; ++m) {
        #pragma unroll
        for (int reg = 0; reg < 4; ++reg) {
            int lr = wm * 128 + m * 16 + (lane >> 4) * 4 + reg;
            #pragma unroll
            for (int n = 0; n < 4; ++n) {
                int lc = wn * 64 + n * 16 + (lane & 15);
                float v = acc[m][n][reg];
                size_t idx = ((size_t)bm * 256 + lr) * (size_t)N + bn * 256 + lc;
                float x = v + bias[bn * 256 + lc];
                if (EPI == 1) {
                    Cb[idx] = f2bf(x / (1.f + __expf(-x)));
                } else {
                    float hv = Cf[idx] + rscale * x;
                    Cf[idx] = hv;
                    if (writeHb) Cb[idx] = f2bf(hv);
                }
            }
        }
    }
}

// ---------------------------------------------------------------------------
// 128x128x(BK=64) bf16 MFMA GEMM (small shapes), double-buffered, 2-phase.
// EPI: 0 = +bias, GELU -> Cf (fp32)
//      3 = bucketed head: gathered A rows, out = . + bias (fp32), masked
template<int EPI>
__global__ __launch_bounds__(256)
void gemm_k(const short* __restrict__ A, const short* __restrict__ BT,
            const float* __restrict__ bias,
            float* __restrict__ Cf,
            const int* __restrict__ counts, const int* __restrict__ bucket,
            float* __restrict__ outp,
            int N, int K, int ntN)
{
    __shared__ short lsA[2][128 * 64];
    __shared__ short lsB[2][128 * 64];
    __shared__ int rowsLds[128];

    int tid = threadIdx.x;
    int w = tid >> 6, lane = tid & 63;

    int bm = 0, bn = 0, m0 = 0, cnt = 0;
    if (EPI == 3) {
        int cls = blockIdx.z;
        cnt = counts[cls * 32];
        if (cnt > MAXM_PER_CLASS) cnt = MAXM_PER_CLASS;
        m0 = blockIdx.y * 128;
        if (m0 >= cnt) return;                       // uniform exit (before any barrier)
        bn = blockIdx.x;
        if (tid < 128) rowsLds[tid] = bucket[cls * MAXM_PER_CLASS + m0 + tid];
        __syncthreads();
        BT   += (size_t)cls * OUTD * WIDTH;
        bias += cls * OUTD;
    } else {
        int nwg = gridDim.x;
        int wg  = blockIdx.x;
        int cpx = nwg >> 3;
        int swz = (wg & 7) * cpx + (wg >> 3);
        bm = swz / ntN; bn = swz % ntN;
    }

    const int sr = lane >> 3;
    const int ss = lane & 7;
    const int wm = w >> 1, wn = w & 1;
    const int nkt = K >> 6;

    f32x4 acc[4][4];
    #pragma unroll
    for (int i = 0; i < 4; ++i)
        #pragma unroll
        for (int j = 0; j < 4; ++j) acc[i][j] = (f32x4)(0.f);

    auto STAGE = [&](int buf, int kt) {
        #pragma unroll
        for (int c = 0; c < 4; ++c) {
            int r  = w * 32 + c * 8 + sr;
            int sg = ss ^ (r & 7);
            long grow = (EPI == 3) ? (long)rowsLds[r] : ((long)bm * 128 + r);
            const short* ga = A + (size_t)grow * K + (size_t)kt * 64 + sg * 8;
            gload_lds16(ga, &lsA[buf][(w * 32 + c * 8) * 64]);
        }
        #pragma unroll
        for (int c = 0; c < 4; ++c) {
            int r  = w * 32 + c * 8 + sr;
            int sg = ss ^ (r & 7);
            const short* gb = BT + (size_t)(bn * 128 + r) * K + (size_t)kt * 64 + sg * 8;
            gload_lds16(gb, &lsB[buf][(w * 32 + c * 8) * 64]);
        }
    };

    STAGE(0, 0);
    VM0();
    __builtin_amdgcn_s_barrier();

    int cur = 0;
    for (int kt = 0; kt < nkt; ++kt) {
        if (kt + 1 < nkt) STAGE(cur ^ 1, kt + 1);

        #pragma unroll
        for (int ks = 0; ks < 2; ++ks) {
            short8 af[4], bf[4];
            #pragma unroll
            for (int m = 0; m < 4; ++m) {
                int r = wm * 64 + m * 16 + (lane & 15);
                int s = ks * 4 + (lane >> 4);
                af[m] = *(const short8*)&lsA[cur][r * 64 + (s ^ (r & 7)) * 8];
            }
            #pragma unroll
            for (int n = 0; n < 4; ++n) {
                int r = wn * 64 + n * 16 + (lane & 15);
                int s = ks * 4 + (lane >> 4);
                bf[n] = *(const short8*)&lsB[cur][r * 64 + (s ^ (r & 7)) * 8];
            }
            __builtin_amdgcn_s_setprio(1);
            #pragma unroll
            for (int m = 0; m < 4; ++m)
                #pragma unroll
                for (int n = 0; n < 4; ++n)
                    acc[m][n] = __builtin_amdgcn_mfma_f32_16x16x32_bf16(af[m], bf[n], acc[m][n], 0, 0, 0);
            __builtin_amdgcn_s_setprio(0);
        }

        VM0();
        __builtin_amdgcn_s_barrier();
        cur ^= 1;
    }

    #pragma unroll
    for (int m = 0; m < 4; ++m) {
        #pragma unroll
        for (int reg = 0; reg < 4; ++reg) {
            int lr = wm * 64 + m * 16 + (lane >> 4) * 4 + reg;
            #pragma unroll
            for (int n = 0; n < 4; ++n) {
                int lc = wn * 64 + n * 16 + (lane & 15);
                float v = acc[m][n][reg];
                if (EPI == 0) {
                    size_t idx = ((size_t)bm * 128 + lr) * (size_t)N + bn * 128 + lc;
                    float x = v + bias[bn * 128 + lc];
                    Cf[idx] = 0.5f * x * (1.f + erff(x * 0.70710678118f));
                } else {
                    if (m0 + lr < cnt) {
                        int orow = rowsLds[lr];
                        int oc = bn * 128 + lc;
                        outp[(size_t)orow * OUTD + oc] = v + bias[oc];
                    }
                }
            }
        }
    }
}

// ---------------------------------------------------------------------------
extern "C" void kernel_launch(void* const* d_in, const int* in_sizes, int n_in,
                              void* d_out, int out_size, void* d_ws, size_t ws_size,
                              hipStream_t stream)
{
    const float* theta = (const float*)d_in[0];
    const float* lam   = (const float*)d_in[1];
    const float* yoh   = (const float*)d_in[2];
    const float* W_in  = (const float*)d_in[3];
    const float* b_in  = (const float*)d_in[4];
    const float* ln_g  = (const float*)d_in[5];
    const float* ln_b  = (const float*)d_in[6];
    const float* w1    = (const float*)d_in[7];
    const float* b1    = (const float*)d_in[8];
    const float* w2    = (const float*)d_in[9];
    const float* b2    = (const float*)d_in[10];
    const float* rsc   = (const float*)d_in[11];
    const float* Wh    = (const float*)d_in[12];
    const float* bh    = (const float*)d_in[13];
    float* out = (float*)d_out;

    char* p = (char*)d_ws;
    auto alloc = [&](size_t bytes) -> char* {
        char* r = p; p += (bytes + 255) & ~(size_t)255; return r;
    };
    float*          h    = (float*)         alloc((size_t)B_ROWS * WIDTH * 4);
    unsigned short* hb   = (unsigned short*)alloc((size_t)B_ROWS * WIDTH * 2);
    unsigned short* z    = (unsigned short*)alloc((size_t)B_ROWS * WIDTH * 2);
    unsigned short* t    = (unsigned short*)alloc((size_t)B_ROWS * HID * 2);
    unsigned short* xb   = (unsigned short*)alloc((size_t)B_ROWS * KIN * 2);
    unsigned short* w1T  = (unsigned short*)alloc((size_t)NBLK * HID * WIDTH * 2);
    unsigned short* w2T  = (unsigned short*)alloc((size_t)NBLK * WIDTH * HID * 2);
    unsigned short* WhT  = (unsigned short*)alloc((size_t)YDIM * OUTD * WIDTH * 2);
    unsigned short* WiT  = (unsigned short*)alloc((size_t)WIDTH * KIN * 2);
    int*            bucket = (int*)alloc((size_t)YDIM * MAXM_PER_CLASS * 4);
    int*            counts = (int*)alloc(16 * 32 * 4);

    hipMemsetAsync(bucket, 0, (size_t)YDIM * MAXM_PER_CLASS * 4, stream);
    hipMemsetAsync(counts, 0, 16 * 32 * 4, stream);

    // prep inputs + buckets
    prep_x_k<<<B_ROWS / 2, 256, 0, stream>>>(theta, lam, yoh, xb);
    bucket_k<<<B_ROWS / 256, 256, 0, stream>>>(yoh, counts, bucket);

    // weight conversions (transpose to [N][K] bf16)
    tcvt_k<<<dim3(WIDTH / 32, KIN / 32, 1),    256, 0, stream>>>(W_in, WiT, 81,   WIDTH, KIN);
    tcvt_k<<<dim3(HID / 32,   WIDTH / 32, 4),  256, 0, stream>>>(w1,   w1T, WIDTH, HID,  WIDTH);
    tcvt_k<<<dim3(WIDTH / 32, HID / 32, 4),    256, 0, stream>>>(w2,   w2T, HID,  WIDTH, HID);
    tcvt_k<<<dim3(OUTD / 32,  WIDTH / 32, 16), 256, 0, stream>>>(Wh,   WhT, WIDTH, OUTD, WIDTH);

    // input GEMM + GELU -> h fp32 (128^2 kernel; K=128 too small for 8-phase)
    gemm_k<0><<<(B_ROWS / 128) * (WIDTH / 128), 256, 0, stream>>>(
        (const short*)xb, (const short*)WiT, b_in, h,
        nullptr, nullptr, nullptr, WIDTH, KIN, WIDTH / 128);

    for (int i = 0; i < NBLK; ++i) {
        ln_k<<<B_ROWS, 256, 0, stream>>>(h, ln_g + i * WIDTH, ln_b + i * WIDTH, z);
        gemm256_k<1><<<(B_ROWS / 256) * (HID / 256), 512, 0, stream>>>(
            (const short*)z, (const short*)(w1T + (size_t)i * HID * WIDTH), b1 + i * HID,
            nullptr, t, nullptr, 0, 0, HID, WIDTH, HID / 256);
        gemm256_k<2><<<(B_ROWS / 256) * (WIDTH / 256), 512, 0, stream>>>(
            (const short*)t, (const short*)(w2T + (size_t)i * WIDTH * HID), b2 + i * WIDTH,
            h, hb, rsc, i, (i == NBLK - 1) ? 1 : 0, WIDTH, HID, WIDTH / 256);
    }

    // bucketed head GEMM
    gemm_k<3><<<dim3(OUTD / 128, MAXM_PER_CLASS / 128, YDIM), 256, 0, stream>>>(
        (const short*)hb, (const short*)WhT, bh, nullptr,
        counts, bucket, out, OUTD, WIDTH, OUTD / 128);

    (void)in_sizes; (void)n_in; (void)out_size; (void)ws_size; (void)rsc;
}